// Round 18
// baseline (276.066 us; speedup 1.0000x reference)
//
#include <hip/hip_runtime.h>

typedef _Float16 f16x8 __attribute__((ext_vector_type(8)));
typedef __attribute__((ext_vector_type(4))) float f32x4;

// ---------- helpers ----------
__device__ __forceinline__ unsigned short f16b(float x){
  _Float16 h = (_Float16)x;
  return __builtin_bit_cast(unsigned short, h);
}
__device__ __forceinline__ void split2h(float x, unsigned short &hi, unsigned short &lo){
  _Float16 h = (_Float16)x;
  _Float16 l = (_Float16)(x - (float)h);
  hi = __builtin_bit_cast(unsigned short, h);
  lo = __builtin_bit_cast(unsigned short, l);
}
__device__ __forceinline__ void gload_lds16(const void* g, void* l){
  __builtin_amdgcn_global_load_lds((const __attribute__((address_space(1))) void*)g,
                                   (__attribute__((address_space(3))) void*)l, 16, 0, 0);
}
#define VM(N)    asm volatile("s_waitcnt vmcnt(" #N ")" ::: "memory")
#define LGKM0()  do { asm volatile("s_waitcnt lgkmcnt(0)" ::: "memory"); \
                      __builtin_amdgcn_sched_barrier(0); } while(0)
#define BAR()    do { __builtin_amdgcn_s_barrier(); \
                      __builtin_amdgcn_sched_barrier(0); } while(0)

// ============================================================================
// 256x256 fp16 GEMM body, BK=64, 512 threads, 2 LDS slots x 64KB (128 KiB).
// R5-verified ledger. Used only for mt split-K (EPI 6).
// ============================================================================
template<int NK, int EPI>
__device__ __forceinline__ void gemm_body(
    const unsigned short* __restrict__ A, const unsigned short* __restrict__ B,
    unsigned short* __restrict__ outp, const float* __restrict__ bias,
    int lda, int ldb, int bm, int bn, char* ldsb)
{
  const int tid  = threadIdx.x;
  const int w    = tid >> 6;
  const int lane = tid & 63;
  const int wm   = w >> 2;              // 0..1
  const int wn   = w & 3;               // 0..3
  const int l15  = lane & 15;
  const int lg   = lane >> 4;

  int srow[2], slg[2];
#pragma unroll
  for (int j = 0; j < 2; j++){
    int o16 = j * 512 + tid;
    int p = o16 >> 3, s = o16 & 7;
    int q = s ^ (p & 7);
    srow[j] = 2 * p + (q >> 2);
    slg[j]  = q & 3;
  }
  const unsigned short* aS0 = A + (size_t)(bm * 256 + srow[0]) * lda + slg[0] * 8;
  const unsigned short* aS1 = A + (size_t)(bm * 256 + srow[1]) * lda + slg[1] * 8;
  const unsigned short* bS0 = B + (size_t)(bn * 256 + srow[0]) * ldb + slg[0] * 8;
  const unsigned short* bS1 = B + (size_t)(bn * 256 + srow[1]) * ldb + slg[1] * 8;

  const int sA   = (((l15 & 1) << 2) | lg) ^ ((l15 >> 1) & 7);
  const int rps  = (l15 >> 1) * 128 + sA * 16;

  f32x4 acc[8][4];
  f32x4 zero = {0.f, 0.f, 0.f, 0.f};
#pragma unroll
  for (int m = 0; m < 8; m++)
#pragma unroll
    for (int n = 0; n < 4; n++) acc[m][n] = zero;

  auto STAGE_Q = [&](int t, int q){
    char* slot = ldsb + (size_t)(t & 1) * 65536;
    const int kb = t * 64;
    if (q == 0){
      gload_lds16(aS0 + kb,      slot +         w * 1024);
      gload_lds16(aS1 + kb,      slot +  8192 + w * 1024);
    } else if (q == 1){
      gload_lds16(bS0 + kb,      slot + 32768 + w * 1024);
      gload_lds16(bS1 + kb,      slot + 40960 + w * 1024);
    } else if (q == 2){
      gload_lds16(bS0 + kb + 32, slot + 49152 + w * 1024);
      gload_lds16(bS1 + kb + 32, slot + 57344 + w * 1024);
    } else {
      gload_lds16(aS0 + kb + 32, slot + 16384 + w * 1024);
      gload_lds16(aS1 + kb + 32, slot + 24576 + w * 1024);
    }
  };

  STAGE_Q(0, 0); STAGE_Q(0, 1); STAGE_Q(0, 2); STAGE_Q(0, 3);

#pragma unroll 1
  for (int t = 0; t < NK; t++){
    const char* sb = ldsb + (size_t)(t & 1) * 65536;
    const bool pre = (t + 1 < NK);
    f16x8 aF[4], bF[4], aG[4], bF2[4], aF2[4], aG2[4];

    VM(4);                              // gate1: q0,q1(t) landed
    BAR();
    if (pre) STAGE_Q(t + 1, 0);
#pragma unroll
    for (int m = 0; m < 4; m++) aF[m] = *(const f16x8*)(sb + wm * 8192 + m * 1024 + rps);
#pragma unroll
    for (int n = 0; n < 4; n++) bF[n] = *(const f16x8*)(sb + 32768 + wn * 4096 + n * 1024 + rps);
    LGKM0();
    __builtin_amdgcn_s_setprio(1);
#pragma unroll
    for (int m = 0; m < 4; m++)
#pragma unroll
      for (int n = 0; n < 4; n++)
        acc[m][n] = __builtin_amdgcn_mfma_f32_16x16x32_f16(aF[m], bF[n], acc[m][n], 0, 0, 0);
    __builtin_amdgcn_s_setprio(0);
    if (pre) STAGE_Q(t + 1, 1);
#pragma unroll
    for (int m = 0; m < 4; m++) aG[m] = *(const f16x8*)(sb + wm * 8192 + (m + 4) * 1024 + rps);
    LGKM0();
    __builtin_amdgcn_s_setprio(1);
#pragma unroll
    for (int m = 0; m < 4; m++)
#pragma unroll
      for (int n = 0; n < 4; n++)
        acc[m + 4][n] = __builtin_amdgcn_mfma_f32_16x16x32_f16(aG[m], bF[n], acc[m + 4][n], 0, 0, 0);
    __builtin_amdgcn_s_setprio(0);

    if (pre) { VM(4); } else { VM(0); } // gate2: q2,q3(t) landed
    BAR();
    if (pre) STAGE_Q(t + 1, 2);
#pragma unroll
    for (int m = 0; m < 4; m++) aF2[m] = *(const f16x8*)(sb + 16384 + wm * 8192 + m * 1024 + rps);
#pragma unroll
    for (int n = 0; n < 4; n++) bF2[n] = *(const f16x8*)(sb + 49152 + wn * 4096 + n * 1024 + rps);
    LGKM0();
    __builtin_amdgcn_s_setprio(1);
#pragma unroll
    for (int m = 0; m < 4; m++)
#pragma unroll
      for (int n = 0; n < 4; n++)
        acc[m][n] = __builtin_amdgcn_mfma_f32_16x16x32_f16(aF2[m], bF2[n], acc[m][n], 0, 0, 0);
    __builtin_amdgcn_s_setprio(0);
    if (pre) STAGE_Q(t + 1, 3);
#pragma unroll
    for (int m = 0; m < 4; m++) aG2[m] = *(const f16x8*)(sb + 16384 + wm * 8192 + (m + 4) * 1024 + rps);
    LGKM0();
    __builtin_amdgcn_s_setprio(1);
#pragma unroll
    for (int m = 0; m < 4; m++)
#pragma unroll
      for (int n = 0; n < 4; n++)
        acc[m + 4][n] = __builtin_amdgcn_mfma_f32_16x16x32_f16(aG2[m], bF2[n], acc[m + 4][n], 0, 0, 0);
    __builtin_amdgcn_s_setprio(0);
  }

#pragma unroll
  for (int m = 0; m < 8; m++)
#pragma unroll
    for (int n = 0; n < 4; n++){
      const int col  = bn * 256 + wn * 64 + n * 16 + l15;
      const int row0 = bm * 256 + wm * 128 + m * 16 + lg * 4;
      float* of = (float*)outp;
#pragma unroll
      for (int q = 0; q < 4; q++)
        of[(size_t)col * 1024 + row0 + q] = acc[m][n][q];
    }
}

// ============================================================================
// 256x256 fp16 GEMM body, BK=32, 512 threads, 2 LDS slots x 32KB = 64 KiB
// -> 2 blocks/CU (cross-block overlap hides the drain stalls).
// Slot = [A 16K | B 16K]; A region = [256 rows][32 k] in the SAME packed
// swizzle as the R15 A.k0 region (read/stage formulas identical).
// Drain ledger (race-free by construction): per tile
//   VM(0) -> BAR  (stage(t) landed for all waves; slot (t+1)&1's tile t-1
//                  reads all retired before this BAR)
//   stage(t+1) into opposite slot ; 12 ds_read ; LGKM0 ; 32 MFMA.
// EPI 4: fp16(acc) row-major, stride 2048 (y). EPI 7: fp16(acc+bias[row])
// row-major, stride 32768 (featsT swapped).
// ============================================================================
template<int NK, int EPI>
__device__ __forceinline__ void gemm_body32(
    const unsigned short* __restrict__ A, const unsigned short* __restrict__ B,
    unsigned short* __restrict__ outp, const float* __restrict__ bias,
    int lda, int ldb, int bm, int bn, char* ldsb)
{
  const int tid  = threadIdx.x;
  const int w    = tid >> 6;
  const int lane = tid & 63;
  const int wm   = w >> 2;              // 0..1
  const int wn   = w & 3;               // 0..3
  const int l15  = lane & 15;
  const int lg   = lane >> 4;

  int srow[2], slg[2];
#pragma unroll
  for (int j = 0; j < 2; j++){
    int o16 = j * 512 + tid;
    int p = o16 >> 3, s = o16 & 7;
    int q = s ^ (p & 7);
    srow[j] = 2 * p + (q >> 2);
    slg[j]  = q & 3;
  }
  const unsigned short* aS0 = A + (size_t)(bm * 256 + srow[0]) * lda + slg[0] * 8;
  const unsigned short* aS1 = A + (size_t)(bm * 256 + srow[1]) * lda + slg[1] * 8;
  const unsigned short* bS0 = B + (size_t)(bn * 256 + srow[0]) * ldb + slg[0] * 8;
  const unsigned short* bS1 = B + (size_t)(bn * 256 + srow[1]) * ldb + slg[1] * 8;

  const int sA   = (((l15 & 1) << 2) | lg) ^ ((l15 >> 1) & 7);
  const int rps  = (l15 >> 1) * 128 + sA * 16;

  f32x4 acc[8][4];
  f32x4 zero = {0.f, 0.f, 0.f, 0.f};
#pragma unroll
  for (int m = 0; m < 8; m++)
#pragma unroll
    for (int n = 0; n < 4; n++) acc[m][n] = zero;

  auto STAGE_T = [&](int t){
    char* slot = ldsb + (size_t)(t & 1) * 32768;
    const int kb = t * 32;
    gload_lds16(aS0 + kb, slot +         w * 1024);
    gload_lds16(aS1 + kb, slot +  8192 + w * 1024);
    gload_lds16(bS0 + kb, slot + 16384 + w * 1024);
    gload_lds16(bS1 + kb, slot + 24576 + w * 1024);
  };

  STAGE_T(0);

#pragma unroll 1
  for (int t = 0; t < NK; t++){
    const char* sb = ldsb + (size_t)(t & 1) * 32768;
    VM(0);                              // stage(t) drained (only outstanding set)
    BAR();                              // certified for all waves; old slot free
    if (t + 1 < NK) STAGE_T(t + 1);
    f16x8 aF[8], bF[4];
#pragma unroll
    for (int m = 0; m < 8; m++) aF[m] = *(const f16x8*)(sb + wm * 8192 + m * 1024 + rps);
#pragma unroll
    for (int n = 0; n < 4; n++) bF[n] = *(const f16x8*)(sb + 16384 + wn * 4096 + n * 1024 + rps);
    LGKM0();
    __builtin_amdgcn_s_setprio(1);
#pragma unroll
    for (int m = 0; m < 8; m++)
#pragma unroll
      for (int n = 0; n < 4; n++)
        acc[m][n] = __builtin_amdgcn_mfma_f32_16x16x32_f16(aF[m], bF[n], acc[m][n], 0, 0, 0);
    __builtin_amdgcn_s_setprio(0);
  }

#pragma unroll
  for (int m = 0; m < 8; m++)
#pragma unroll
    for (int n = 0; n < 4; n++){
      const int col  = bn * 256 + wn * 64 + n * 16 + l15;
      const int row0 = bm * 256 + wm * 128 + m * 16 + lg * 4;
      if (EPI == 4){
#pragma unroll
        for (int q = 0; q < 4; q++)
          outp[(size_t)(row0 + q) * 2048 + col] = f16b(acc[m][n][q]);
      } else {
#pragma unroll
        for (int q = 0; q < 4; q++)
          outp[(size_t)(row0 + q) * 32768 + col] = f16b(acc[m][n][q] + bias[row0 + q]);
      }
    }
}

// ============================================================================
// Merged big-GEMM launch, INTERLEAVED halves (x2 L2 sharing, R17-verified),
// BK=32 bodies at 64 KiB LDS -> 2 blocks/CU.
// ============================================================================
__global__ __launch_bounds__(512, 2) void k_big(
    const unsigned short* __restrict__ x2, const unsigned short* __restrict__ MTh,
    unsigned short* __restrict__ y2, const unsigned short* __restrict__ WgTh,
    unsigned short* __restrict__ FT, const float* __restrict__ bg)
{
  __shared__ __align__(16) unsigned short lds_u[32768];   // 64 KiB
  const int b = blockIdx.x;              // 0..1023
  int k = b >> 1;                        // 0..511
  k = (k & 7) * 64 + (k >> 3);           // XCD swizzle over 512 tile-pairs
  if ((b & 1) == 0){
    gemm_body32<32, 4>(x2, MTh, y2, nullptr, 1024, 1024, k >> 2, k & 3, (char*)lds_u);
  } else {
    gemm_body32<32, 7>(WgTh, x2, FT, bg, 1024, 1024, k & 3, k >> 2, (char*)lds_u);
  }
}

// ============================================================================
// Fused launch: blocks [0,96) = M split-K partials (3 seg x 2 kc x 16 tiles,
// K=512 NK=8, EPI 6); blocks [96,1120) = split_x (hi-only, memory-bound).
// (byte-identical to R17 — verified)
// ============================================================================
__global__ __launch_bounds__(512, 1) void k_mtx(
    const unsigned short* __restrict__ Wa2, const unsigned short* __restrict__ Wb2,
    float* __restrict__ Mpart,
    const float* __restrict__ x, unsigned short* __restrict__ x2,
    const float* __restrict__ wv, float* __restrict__ v)
{
  __shared__ __align__(16) unsigned short lds_u[65536];
  const int b = blockIdx.x;
  if (b < 96){
    const int s = b >> 5, rest = b & 31;
    const int kc = rest >> 4, tile = rest & 15;
    const unsigned short* Aa = Wa2 + (s == 1 ? 1024 : 0) + kc * 512;  // Wal for seg1
    const unsigned short* Bb = Wb2 + (s == 2 ? 1024 : 0) + kc * 512;  // Wbl for seg2
    gemm_body<8, 6>(Aa, Bb, (unsigned short*)(Mpart + (size_t)(s * 2 + kc) * 1048576),
                    nullptr, 2048, 2048, tile >> 2, tile & 3, (char*)lds_u);
  } else {
    const int bb = b - 96;                       // 0..1023
    const int w = threadIdx.x >> 6, lane = threadIdx.x & 63;
#pragma unroll
    for (int it = 0; it < 4; it++){
      const int row = bb * 8 + w + it * 8192;
      float s = 0.f;
#pragma unroll
      for (int j = 0; j < 4; j++){
        const int c = lane * 4 + j * 256;
        float4 val = *(const float4*)(x + (size_t)row * 1024 + c);
        float4 wvv = *(const float4*)(wv + c);
        ushort4 h, l;
        split2h(val.x, h.x, l.x); split2h(val.y, h.y, l.y);
        split2h(val.z, h.z, l.z); split2h(val.w, h.w, l.w);
        *(ushort4*)(x2 + (size_t)row * 1024 + c) = h;   // hi only
        s += val.x * wvv.x + val.y * wvv.y + val.z * wvv.z + val.w * wvv.w;
      }
      for (int o = 32; o; o >>= 1) s += __shfl_xor(s, o);
      if (lane == 0) v[row] = s;
    }
  }
}

// MTh[i] = fp16(sum of 6 partials); grid 1024 x 256 x float4.
__global__ __launch_bounds__(256) void k_mt_reduce(const float* __restrict__ P,
                                                   unsigned short* __restrict__ MTh){
  const size_t i = ((size_t)blockIdx.x * 256 + threadIdx.x) * 4;
  float4 s = *(const float4*)(P + i);
#pragma unroll
  for (int p = 1; p < 6; p++){
    float4 a = *(const float4*)(P + (size_t)p * 1048576 + i);
    s.x += a.x; s.y += a.y; s.z += a.z; s.w += a.w;
  }
  ushort4 h;
  h.x = f16b(s.x); h.y = f16b(s.y); h.z = f16b(s.z); h.w = f16b(s.w);
  *(ushort4*)(MTh + i) = h;
}

// ============================================================================
// Fused per-frame kernel, 1024 threads (16 waves), LDS 96 KiB.
// (byte-identical to R17 — verified)
// ============================================================================
__global__ __launch_bounds__(1024) void k_frame(
    const unsigned short* Y2, const unsigned short* X2,
    const float* __restrict__ v, const unsigned short* __restrict__ FT,
    float* outp)
{
  __shared__ __align__(16) unsigned short lds_u[49152];   // 96 KiB
  char* ldsb = (char*)lds_u;

  const int frame = blockIdx.x;
  const int tid  = threadIdx.x;
  const int w    = tid >> 6;        // 0..15
  const int lane = tid & 63;
  const int wm   = w >> 2;          // 0..3
  const int wn   = w & 3;           // 0..3
  const int l15  = lane & 15;
  const int lg   = lane >> 4;

  const int cS = tid & 511, hS = tid >> 9;
  const int pS = cS >> 3, sS = cS & 7;
  const int qS = sS ^ (pS & 7);
  const int srow = 2 * pS + (qS >> 2);
  const int slg  = qS & 3;
  const unsigned short* yS = Y2 + (size_t)(frame * 128 + srow) * 2048 + slg * 8;
  const unsigned short* xS = X2 + (size_t)(frame * 128 + srow) * 1024 + slg * 8;
  const int dY =         hS * 8192 + cS * 16;
  const int dX = 16384 + hS * 8192 + cS * 16;

  const int sA  = (((l15 & 1) << 2) | lg) ^ ((l15 >> 1) & 7);
  const int rps = (l15 >> 1) * 128 + sA * 16;

  f32x4 acc[2][2];
  f32x4 zero = {0.f, 0.f, 0.f, 0.f};
#pragma unroll
  for (int m = 0; m < 2; m++)
#pragma unroll
    for (int n = 0; n < 2; n++) acc[m][n] = zero;

  auto STAGE_K = [&](int t){
    char* slot = ldsb + (size_t)(t & 1) * 32768;
    const int kk = t * 64 + hS * 32;
    gload_lds16(yS + kk, slot + dY);
    gload_lds16(xS + kk, slot + dX);
  };

  const int NK = 16;
  STAGE_K(0);

#pragma unroll 1
  for (int t = 0; t < NK; t++){
    const char* sb = ldsb + (size_t)(t & 1) * 32768;
    if (t + 1 < NK){ STAGE_K(t + 1); VM(2); } else { VM(0); }
    BAR();
    f16x8 aF[2][2], bh[2][2];
#pragma unroll
    for (int h = 0; h < 2; h++){
#pragma unroll
      for (int m = 0; m < 2; m++)
        aF[h][m] = *(const f16x8*)(sb + h * 8192 + (wm * 2 + m) * 1024 + rps);
#pragma unroll
      for (int n = 0; n < 2; n++)
        bh[h][n] = *(const f16x8*)(sb + 16384 + h * 8192 + (wn * 2 + n) * 1024 + rps);
    }
    LGKM0();
    __builtin_amdgcn_s_setprio(1);
#pragma unroll
    for (int h = 0; h < 2; h++)
#pragma unroll
      for (int m = 0; m < 2; m++)
#pragma unroll
        for (int n = 0; n < 2; n++)
          acc[m][n] = __builtin_amdgcn_mfma_f32_16x16x32_f16(aF[h][m], bh[h][n], acc[m][n], 0, 0, 0);
    __builtin_amdgcn_s_setprio(0);
    BAR();
  }

  // ---- softmax ----
  BAR();
  float* sf = (float*)ldsb;
#pragma unroll
  for (int m = 0; m < 2; m++)
#pragma unroll
    for (int n = 0; n < 2; n++){
      const int col = wn * 32 + n * 16 + l15;
#pragma unroll
      for (int q = 0; q < 4; q++){
        const int row = wm * 32 + m * 16 + lg * 4 + q;
        sf[row * 128 + ((col + (row & 31) * 4) & 127)] = acc[m][n][q];
      }
    }
  LGKM0(); BAR();
  unsigned short* Pb = (unsigned short*)(ldsb + 65536);
  {
    const float* vr = v + (size_t)frame * 128;
#pragma unroll 1
    for (int i = 0; i < 8; i++){
      const int row = w * 8 + i;
      const float* rp = sf + row * 128;
      const int rot = (row & 31) * 4;
      float a = rp[(lane + rot) & 127]      + vr[lane];
      float b = rp[(lane + 64 + rot) & 127] + vr[lane + 64];
      float mx = fmaxf(a, b);
      for (int o = 32; o; o >>= 1) mx = fmaxf(mx, __shfl_xor(mx, o));
      float ea = __expf(a - mx), eb = __expf(b - mx);
      float s = ea + eb;
      for (int o = 32; o; o >>= 1) s += __shfl_xor(s, o);
      const float inv = 1.0f / s;
      unsigned short* prow = (unsigned short*)((char*)Pb + row * 256);
      const int j0 = lane, j1 = lane + 64;
      *(unsigned short*)((char*)prow + (((j0 >> 3) ^ (row & 15)) * 16) + (j0 & 7) * 2) = f16b(ea * inv);
      *(unsigned short*)((char*)prow + (((j1 >> 3) ^ (row & 15)) * 16) + (j1 & 7) * 2) = f16b(eb * inv);
    }
  }
  LGKM0(); BAR();

  // ---- PV ----
  char* Fb = ldsb;
  auto STAGE_F = [&](int h){
    char* slot = Fb + (size_t)(h & 1) * 32768;
#pragma unroll
    for (int j = 0; j < 2; j++){
      const int o = j * 1024 + tid;
      const int a = o >> 4, c = o & 15;
      gload_lds16(FT + (size_t)(h * 128 + a) * 32768 + frame * 128 + (c ^ (a & 15)) * 8,
                  slot + (size_t)o * 16);
    }
  };
  STAGE_F(0);

#pragma unroll 1
  for (int h = 0; h < 8; h++){
    if (h + 1 < 8){ STAGE_F(h + 1); VM(2); } else { VM(0); }
    BAR();
    const char* fs = Fb + (size_t)(h & 1) * 32768;
    f16x8 pF[4][2], fF[4][2];
#pragma unroll
    for (int ks = 0; ks < 4; ks++){
#pragma unroll
      for (int m = 0; m < 2; m++){
        const int row = wm * 32 + m * 16 + l15;
        pF[ks][m] = *(const f16x8*)((char*)Pb + row * 256 + (((ks * 4 + lg) ^ (row & 15)) * 16));
      }
#pragma unroll
      for (int n = 0; n < 2; n++){
        const int al = wn * 32 + n * 16 + l15;
        fF[ks][n] = *(const f16x8*)(fs + al * 256 + (((ks * 4 + lg) ^ (al & 15)) * 16));
      }
    }
    LGKM0();
    f32x4 accP[2][2];
#pragma unroll
    for (int m = 0; m < 2; m++)
#pragma unroll
      for (int n = 0; n < 2; n++) accP[m][n] = zero;
    __builtin_amdgcn_s_setprio(1);
#pragma unroll
    for (int ks = 0; ks < 4; ks++)
#pragma unroll
      for (int m = 0; m < 2; m++)
#pragma unroll
        for (int n = 0; n < 2; n++)
          accP[m][n] = __builtin_amdgcn_mfma_f32_16x16x32_f16(pF[ks][m], fF[ks][n], accP[m][n], 0, 0, 0);
    __builtin_amdgcn_s_setprio(0);
#pragma unroll
    for (int m = 0; m < 2; m++)
#pragma unroll
      for (int n = 0; n < 2; n++){
        const int f  = h * 128 + wn * 32 + n * 16 + l15;
        const int r0 = wm * 32 + m * 16 + lg * 4;
#pragma unroll
        for (int q = 0; q < 4; q++)
          outp[((size_t)frame * 128 + r0 + q) * 1024 + f] = accP[m][n][q];
      }
    BAR();
  }
}

// ============================================================================
// Merged prep (unchanged).
// ============================================================================
__global__ __launch_bounds__(256) void k_prep(const float* __restrict__ Wa,
                                              const float* __restrict__ Wb,
                                              const float* __restrict__ Wg,
                                              const float* __restrict__ ba,
                                              unsigned short* __restrict__ Wa2,
                                              unsigned short* __restrict__ Wb2,
                                              unsigned short* __restrict__ WgTh,
                                              float* __restrict__ wv){
  const int b = blockIdx.x;
  if (b < 2048){
    const int row = (b < 1024) ? b : (b - 1024);
    const float* src = (b < 1024) ? Wa : Wb;
    unsigned short* dst = (b < 1024) ? Wa2 : Wb2;
    const int c = threadIdx.x * 4;
    float4 val = *(const float4*)(src + (size_t)row * 1024 + c);
    ushort4 h, l;
    split2h(val.x, h.x, l.x); split2h(val.y, h.y, l.y);
    split2h(val.z, h.z, l.z); split2h(val.w, h.w, l.w);
    *(ushort4*)(dst + (size_t)row * 2048 + c) = h;
    *(ushort4*)(dst + (size_t)row * 2048 + 1024 + c) = l;
  } else if (b < 3072){
    const int row = b - 2048;
    const int c0 = threadIdx.x * 4;
    float4 val = *(const float4*)(Wg + (size_t)row * 1024 + c0);
    float vv[4] = {val.x, val.y, val.z, val.w};
#pragma unroll
    for (int i = 0; i < 4; i++)
      WgTh[(size_t)(c0 + i) * 1024 + row] = f16b(vv[i]);
  } else {
    const int row = (b - 3072) * 4 + (threadIdx.x >> 6);
    const int lane = threadIdx.x & 63;
    float s = 0.f;
#pragma unroll
    for (int j = 0; j < 4; j++){
      const int c = lane * 4 + j * 256;
      float4 wb = *(const float4*)(Wb + (size_t)row * 1024 + c);
      float4 bb = *(const float4*)(ba + c);
      s += wb.x * bb.x + wb.y * bb.y + wb.z * bb.z + wb.w * bb.w;
    }
    for (int o = 32; o; o >>= 1) s += __shfl_xor(s, o);
    if (lane == 0) wv[row] = s;
  }
}

// ---------- launcher ----------
extern "C" void kernel_launch(void* const* d_in, const int* in_sizes, int n_in,
                              void* d_out, int out_size, void* d_ws, size_t ws_size,
                              hipStream_t stream) {
  const float* x  = (const float*)d_in[0];
  const float* Wa = (const float*)d_in[2];
  const float* ba = (const float*)d_in[3];
  const float* Wb = (const float*)d_in[4];
  const float* Wg = (const float*)d_in[6];
  const float* bg = (const float*)d_in[7];

  unsigned short* x2   = (unsigned short*)d_ws;            // 32768 x 1024 fp16 (hi)
  unsigned short* Wa2  = x2 + (size_t)32768 * 1024;        // 1024 x 2048
  unsigned short* Wb2  = Wa2 + (size_t)1024 * 2048;        // 1024 x 2048
  unsigned short* WgTh = Wb2 + (size_t)1024 * 2048;        // 1024 x 1024 (Wg^T fp16)
  unsigned short* MTh  = WgTh + (size_t)1024 * 1024;       // 1024 x 1024 (M^T fp16)
  unsigned short* FT   = MTh + (size_t)1024 * 1024;        // 1024 x 32768 (feats^T fp16)
  float* Mpart = (float*)(FT + (size_t)1024 * 32768);      // 6 x 1024x1024 fp32
  float* wv = Mpart + (size_t)6 * 1048576;                 // 1024
  float* v  = wv + 1024;                                   // 32768
  size_t need = (size_t)((char*)(v + 32768) - (char*)d_ws);
  if (ws_size < need) return;

  unsigned short* y2 = (unsigned short*)d_out;             // yh rows, stride 2048

  k_prep      <<<3328, 256, 0, stream>>>(Wa, Wb, Wg, ba, Wa2, Wb2, WgTh, wv);
  // mt split-K (96 compute-bound blocks) hidden under split_x (memory-bound)
  k_mtx       <<<1120, 512, 0, stream>>>(Wa2, Wb2, Mpart, x, x2, wv, v);
  k_mt_reduce <<<1024, 256, 0, stream>>>(Mpart, MTh);
  // y + featsT interleaved; BK=32 bodies, 64 KiB LDS, 2 blocks/CU
  k_big       <<<1024, 512, 0, stream>>>(x2, MTh, y2, WgTh, FT, bg);
  // scores (K=1024: yh x xh) -> softmax -> PV
  k_frame     <<<256, 1024, 0, stream>>>(y2, x2, v, FT, (float*)d_out);
}

// Round 19
// 272.755 us; speedup vs baseline: 1.0121x; 1.0121x over previous
//
#include <hip/hip_runtime.h>

typedef _Float16 f16x8 __attribute__((ext_vector_type(8)));
typedef __attribute__((ext_vector_type(4))) float f32x4;

// ---------- helpers ----------
__device__ __forceinline__ unsigned short f16b(float x){
  _Float16 h = (_Float16)x;
  return __builtin_bit_cast(unsigned short, h);
}
__device__ __forceinline__ void split2h(float x, unsigned short &hi, unsigned short &lo){
  _Float16 h = (_Float16)x;
  _Float16 l = (_Float16)(x - (float)h);
  hi = __builtin_bit_cast(unsigned short, h);
  lo = __builtin_bit_cast(unsigned short, l);
}
__device__ __forceinline__ void gload_lds16(const void* g, void* l){
  __builtin_amdgcn_global_load_lds((const __attribute__((address_space(1))) void*)g,
                                   (__attribute__((address_space(3))) void*)l, 16, 0, 0);
}
#define VM(N)    asm volatile("s_waitcnt vmcnt(" #N ")" ::: "memory")
#define LGKM0()  do { asm volatile("s_waitcnt lgkmcnt(0)" ::: "memory"); \
                      __builtin_amdgcn_sched_barrier(0); } while(0)
#define BAR()    do { __builtin_amdgcn_s_barrier(); \
                      __builtin_amdgcn_sched_barrier(0); } while(0)

// ============================================================================
// 256x256 fp16 GEMM body, BK=64, 512 threads (8 waves 2x4), 2 LDS slots x 64KB.
// R5-verified ledger (best of 6 schedule variants): 2 barriers/tile;
// gate1(t) VM(4) retires q0,q1(t); gate2(t) VM(4) retires q2,q3(t); each gate
// precedes its BAR (cross-wave certified). XOR-swizzled LDS (0 conflicts).
// EPI 4: fp16(acc) row-major write, stride 2048 (y path, half-filled).
// EPI 6: fp32(acc)^T write, stride 1024 (M split-K partial).
// EPI 7: fp16(acc + bias[row]) row-major write, stride 32768 (featsT swapped).
// ============================================================================
template<int NK, int EPI>
__device__ __forceinline__ void gemm_body(
    const unsigned short* __restrict__ A, const unsigned short* __restrict__ B,
    unsigned short* __restrict__ outp, const float* __restrict__ bias,
    int lda, int ldb, int bm, int bn, char* ldsb)
{
  const int tid  = threadIdx.x;
  const int w    = tid >> 6;
  const int lane = tid & 63;
  const int wm   = w >> 2;              // 0..1
  const int wn   = w & 3;               // 0..3
  const int l15  = lane & 15;
  const int lg   = lane >> 4;

  int srow[2], slg[2];
#pragma unroll
  for (int j = 0; j < 2; j++){
    int o16 = j * 512 + tid;
    int p = o16 >> 3, s = o16 & 7;
    int q = s ^ (p & 7);
    srow[j] = 2 * p + (q >> 2);
    slg[j]  = q & 3;
  }
  const unsigned short* aS0 = A + (size_t)(bm * 256 + srow[0]) * lda + slg[0] * 8;
  const unsigned short* aS1 = A + (size_t)(bm * 256 + srow[1]) * lda + slg[1] * 8;
  const unsigned short* bS0 = B + (size_t)(bn * 256 + srow[0]) * ldb + slg[0] * 8;
  const unsigned short* bS1 = B + (size_t)(bn * 256 + srow[1]) * ldb + slg[1] * 8;

  const int sA   = (((l15 & 1) << 2) | lg) ^ ((l15 >> 1) & 7);
  const int rps  = (l15 >> 1) * 128 + sA * 16;

  f32x4 acc[8][4];
  f32x4 zero = {0.f, 0.f, 0.f, 0.f};
#pragma unroll
  for (int m = 0; m < 8; m++)
#pragma unroll
    for (int n = 0; n < 4; n++) acc[m][n] = zero;

  auto STAGE_Q = [&](int t, int q){
    char* slot = ldsb + (size_t)(t & 1) * 65536;
    const int kb = t * 64;
    if (q == 0){
      gload_lds16(aS0 + kb,      slot +         w * 1024);
      gload_lds16(aS1 + kb,      slot +  8192 + w * 1024);
    } else if (q == 1){
      gload_lds16(bS0 + kb,      slot + 32768 + w * 1024);
      gload_lds16(bS1 + kb,      slot + 40960 + w * 1024);
    } else if (q == 2){
      gload_lds16(bS0 + kb + 32, slot + 49152 + w * 1024);
      gload_lds16(bS1 + kb + 32, slot + 57344 + w * 1024);
    } else {
      gload_lds16(aS0 + kb + 32, slot + 16384 + w * 1024);
      gload_lds16(aS1 + kb + 32, slot + 24576 + w * 1024);
    }
  };

  STAGE_Q(0, 0); STAGE_Q(0, 1); STAGE_Q(0, 2); STAGE_Q(0, 3);

#pragma unroll 1
  for (int t = 0; t < NK; t++){
    const char* sb = ldsb + (size_t)(t & 1) * 65536;
    const bool pre = (t + 1 < NK);
    f16x8 aF[4], bF[4], aG[4], bF2[4], aF2[4], aG2[4];

    VM(4);                              // gate1: q0,q1(t) landed
    BAR();
    if (pre) STAGE_Q(t + 1, 0);
#pragma unroll
    for (int m = 0; m < 4; m++) aF[m] = *(const f16x8*)(sb + wm * 8192 + m * 1024 + rps);
#pragma unroll
    for (int n = 0; n < 4; n++) bF[n] = *(const f16x8*)(sb + 32768 + wn * 4096 + n * 1024 + rps);
    LGKM0();
    __builtin_amdgcn_s_setprio(1);
#pragma unroll
    for (int m = 0; m < 4; m++)
#pragma unroll
      for (int n = 0; n < 4; n++)
        acc[m][n] = __builtin_amdgcn_mfma_f32_16x16x32_f16(aF[m], bF[n], acc[m][n], 0, 0, 0);
    __builtin_amdgcn_s_setprio(0);
    if (pre) STAGE_Q(t + 1, 1);
#pragma unroll
    for (int m = 0; m < 4; m++) aG[m] = *(const f16x8*)(sb + wm * 8192 + (m + 4) * 1024 + rps);
    LGKM0();
    __builtin_amdgcn_s_setprio(1);
#pragma unroll
    for (int m = 0; m < 4; m++)
#pragma unroll
      for (int n = 0; n < 4; n++)
        acc[m + 4][n] = __builtin_amdgcn_mfma_f32_16x16x32_f16(aG[m], bF[n], acc[m + 4][n], 0, 0, 0);
    __builtin_amdgcn_s_setprio(0);

    if (pre) { VM(4); } else { VM(0); } // gate2: q2,q3(t) landed
    BAR();
    if (pre) STAGE_Q(t + 1, 2);
#pragma unroll
    for (int m = 0; m < 4; m++) aF2[m] = *(const f16x8*)(sb + 16384 + wm * 8192 + m * 1024 + rps);
#pragma unroll
    for (int n = 0; n < 4; n++) bF2[n] = *(const f16x8*)(sb + 49152 + wn * 4096 + n * 1024 + rps);
    LGKM0();
    __builtin_amdgcn_s_setprio(1);
#pragma unroll
    for (int m = 0; m < 4; m++)
#pragma unroll
      for (int n = 0; n < 4; n++)
        acc[m][n] = __builtin_amdgcn_mfma_f32_16x16x32_f16(aF2[m], bF2[n], acc[m][n], 0, 0, 0);
    __builtin_amdgcn_s_setprio(0);
    if (pre) STAGE_Q(t + 1, 3);
#pragma unroll
    for (int m = 0; m < 4; m++) aG2[m] = *(const f16x8*)(sb + 16384 + wm * 8192 + (m + 4) * 1024 + rps);
    LGKM0();
    __builtin_amdgcn_s_setprio(1);
#pragma unroll
    for (int m = 0; m < 4; m++)
#pragma unroll
      for (int n = 0; n < 4; n++)
        acc[m + 4][n] = __builtin_amdgcn_mfma_f32_16x16x32_f16(aG2[m], bF2[n], acc[m + 4][n], 0, 0, 0);
    __builtin_amdgcn_s_setprio(0);
  }

#pragma unroll
  for (int m = 0; m < 8; m++)
#pragma unroll
    for (int n = 0; n < 4; n++){
      const int col  = bn * 256 + wn * 64 + n * 16 + l15;
      const int row0 = bm * 256 + wm * 128 + m * 16 + lg * 4;
      if (EPI == 4){
#pragma unroll
        for (int q = 0; q < 4; q++)
          outp[(size_t)(row0 + q) * 2048 + col] = f16b(acc[m][n][q]);
      } else if (EPI == 6){
        float* of = (float*)outp;
#pragma unroll
        for (int q = 0; q < 4; q++)
          of[(size_t)col * 1024 + row0 + q] = acc[m][n][q];
      } else if (EPI == 7){
#pragma unroll
        for (int q = 0; q < 4; q++)
          outp[(size_t)(row0 + q) * 32768 + col] = f16b(acc[m][n][q] + bias[row0 + q]);
      }
    }
}

// ============================================================================
// Merged big-GEMM launch, INTERLEAVED halves for x2 L2 sharing (R17-verified):
// even b -> y tile k=b>>1; odd b -> featsT tile sharing the same x2 panel.
// ============================================================================
__global__ __launch_bounds__(512, 2) void k_big(
    const unsigned short* __restrict__ x2, const unsigned short* __restrict__ MTh,
    unsigned short* __restrict__ y2, const unsigned short* __restrict__ WgTh,
    unsigned short* __restrict__ FT, const float* __restrict__ bg)
{
  __shared__ __align__(16) unsigned short lds_u[65536];
  const int b = blockIdx.x;              // 0..1023
  int k = b >> 1;                        // 0..511
  k = (k & 7) * 64 + (k >> 3);           // XCD swizzle over 512 tile-pairs
  if ((b & 1) == 0){
    gemm_body<16, 4>(x2, MTh, y2, nullptr, 1024, 1024, k >> 2, k & 3, (char*)lds_u);
  } else {
    gemm_body<16, 7>(WgTh, x2, FT, bg, 1024, 1024, k & 3, k >> 2, (char*)lds_u);
  }
}

// ============================================================================
// Fused launch: blocks [0,96) = M split-K partials (3 seg x 2 kc x 16 tiles,
// K=512 NK=8, EPI 6); blocks [96,1120) = split_x (hi-only, memory-bound).
// ============================================================================
__global__ __launch_bounds__(512, 1) void k_mtx(
    const unsigned short* __restrict__ Wa2, const unsigned short* __restrict__ Wb2,
    float* __restrict__ Mpart,
    const float* __restrict__ x, unsigned short* __restrict__ x2,
    const float* __restrict__ wv, float* __restrict__ v)
{
  __shared__ __align__(16) unsigned short lds_u[65536];
  const int b = blockIdx.x;
  if (b < 96){
    const int s = b >> 5, rest = b & 31;
    const int kc = rest >> 4, tile = rest & 15;
    const unsigned short* Aa = Wa2 + (s == 1 ? 1024 : 0) + kc * 512;  // Wal for seg1
    const unsigned short* Bb = Wb2 + (s == 2 ? 1024 : 0) + kc * 512;  // Wbl for seg2
    gemm_body<8, 6>(Aa, Bb, (unsigned short*)(Mpart + (size_t)(s * 2 + kc) * 1048576),
                    nullptr, 2048, 2048, tile >> 2, tile & 3, (char*)lds_u);
  } else {
    const int bb = b - 96;                       // 0..1023
    const int w = threadIdx.x >> 6, lane = threadIdx.x & 63;
#pragma unroll
    for (int it = 0; it < 4; it++){
      const int row = bb * 8 + w + it * 8192;
      float s = 0.f;
#pragma unroll
      for (int j = 0; j < 4; j++){
        const int c = lane * 4 + j * 256;
        float4 val = *(const float4*)(x + (size_t)row * 1024 + c);
        float4 wvv = *(const float4*)(wv + c);
        ushort4 h, l;
        split2h(val.x, h.x, l.x); split2h(val.y, h.y, l.y);
        split2h(val.z, h.z, l.z); split2h(val.w, h.w, l.w);
        *(ushort4*)(x2 + (size_t)row * 1024 + c) = h;   // hi only
        s += val.x * wvv.x + val.y * wvv.y + val.z * wvv.z + val.w * wvv.w;
      }
      for (int o = 32; o; o >>= 1) s += __shfl_xor(s, o);
      if (lane == 0) v[row] = s;
    }
  }
}

// MTh[i] = fp16(sum of 6 partials); grid 1024 x 256 x float4.
__global__ __launch_bounds__(256) void k_mt_reduce(const float* __restrict__ P,
                                                   unsigned short* __restrict__ MTh){
  const size_t i = ((size_t)blockIdx.x * 256 + threadIdx.x) * 4;
  float4 s = *(const float4*)(P + i);
#pragma unroll
  for (int p = 1; p < 6; p++){
    float4 a = *(const float4*)(P + (size_t)p * 1048576 + i);
    s.x += a.x; s.y += a.y; s.z += a.z; s.w += a.w;
  }
  ushort4 h;
  h.x = f16b(s.x); h.y = f16b(s.y); h.z = f16b(s.z); h.w = f16b(s.w);
  *(ushort4*)(MTh + i) = h;
}

// ============================================================================
// Fused per-frame kernel, 1024 threads (16 waves), LDS 96 KiB.
// (byte-identical to R17 — verified)
// ============================================================================
__global__ __launch_bounds__(1024) void k_frame(
    const unsigned short* Y2, const unsigned short* X2,
    const float* __restrict__ v, const unsigned short* __restrict__ FT,
    float* outp)
{
  __shared__ __align__(16) unsigned short lds_u[49152];   // 96 KiB
  char* ldsb = (char*)lds_u;

  const int frame = blockIdx.x;
  const int tid  = threadIdx.x;
  const int w    = tid >> 6;        // 0..15
  const int lane = tid & 63;
  const int wm   = w >> 2;          // 0..3
  const int wn   = w & 3;           // 0..3
  const int l15  = lane & 15;
  const int lg   = lane >> 4;

  const int cS = tid & 511, hS = tid >> 9;
  const int pS = cS >> 3, sS = cS & 7;
  const int qS = sS ^ (pS & 7);
  const int srow = 2 * pS + (qS >> 2);
  const int slg  = qS & 3;
  const unsigned short* yS = Y2 + (size_t)(frame * 128 + srow) * 2048 + slg * 8;
  const unsigned short* xS = X2 + (size_t)(frame * 128 + srow) * 1024 + slg * 8;
  const int dY =         hS * 8192 + cS * 16;
  const int dX = 16384 + hS * 8192 + cS * 16;

  const int sA  = (((l15 & 1) << 2) | lg) ^ ((l15 >> 1) & 7);
  const int rps = (l15 >> 1) * 128 + sA * 16;

  f32x4 acc[2][2];
  f32x4 zero = {0.f, 0.f, 0.f, 0.f};
#pragma unroll
  for (int m = 0; m < 2; m++)
#pragma unroll
    for (int n = 0; n < 2; n++) acc[m][n] = zero;

  auto STAGE_K = [&](int t){
    char* slot = ldsb + (size_t)(t & 1) * 32768;
    const int kk = t * 64 + hS * 32;
    gload_lds16(yS + kk, slot + dY);
    gload_lds16(xS + kk, slot + dX);
  };

  const int NK = 16;
  STAGE_K(0);

#pragma unroll 1
  for (int t = 0; t < NK; t++){
    const char* sb = ldsb + (size_t)(t & 1) * 32768;
    if (t + 1 < NK){ STAGE_K(t + 1); VM(2); } else { VM(0); }
    BAR();
    f16x8 aF[2][2], bh[2][2];
#pragma unroll
    for (int h = 0; h < 2; h++){
#pragma unroll
      for (int m = 0; m < 2; m++)
        aF[h][m] = *(const f16x8*)(sb + h * 8192 + (wm * 2 + m) * 1024 + rps);
#pragma unroll
      for (int n = 0; n < 2; n++)
        bh[h][n] = *(const f16x8*)(sb + 16384 + h * 8192 + (wn * 2 + n) * 1024 + rps);
    }
    LGKM0();
    __builtin_amdgcn_s_setprio(1);
#pragma unroll
    for (int h = 0; h < 2; h++)
#pragma unroll
      for (int m = 0; m < 2; m++)
#pragma unroll
        for (int n = 0; n < 2; n++)
          acc[m][n] = __builtin_amdgcn_mfma_f32_16x16x32_f16(aF[h][m], bh[h][n], acc[m][n], 0, 0, 0);
    __builtin_amdgcn_s_setprio(0);
    BAR();
  }

  // ---- softmax ----
  BAR();
  float* sf = (float*)ldsb;
#pragma unroll
  for (int m = 0; m < 2; m++)
#pragma unroll
    for (int n = 0; n < 2; n++){
      const int col = wn * 32 + n * 16 + l15;
#pragma unroll
      for (int q = 0; q < 4; q++){
        const int row = wm * 32 + m * 16 + lg * 4 + q;
        sf[row * 128 + ((col + (row & 31) * 4) & 127)] = acc[m][n][q];
      }
    }
  LGKM0(); BAR();
  unsigned short* Pb = (unsigned short*)(ldsb + 65536);
  {
    const float* vr = v + (size_t)frame * 128;
#pragma unroll 1
    for (int i = 0; i < 8; i++){
      const int row = w * 8 + i;
      const float* rp = sf + row * 128;
      const int rot = (row & 31) * 4;
      float a = rp[(lane + rot) & 127]      + vr[lane];
      float b = rp[(lane + 64 + rot) & 127] + vr[lane + 64];
      float mx = fmaxf(a, b);
      for (int o = 32; o; o >>= 1) mx = fmaxf(mx, __shfl_xor(mx, o));
      float ea = __expf(a - mx), eb = __expf(b - mx);
      float s = ea + eb;
      for (int o = 32; o; o >>= 1) s += __shfl_xor(s, o);
      const float inv = 1.0f / s;
      unsigned short* prow = (unsigned short*)((char*)Pb + row * 256);
      const int j0 = lane, j1 = lane + 64;
      *(unsigned short*)((char*)prow + (((j0 >> 3) ^ (row & 15)) * 16) + (j0 & 7) * 2) = f16b(ea * inv);
      *(unsigned short*)((char*)prow + (((j1 >> 3) ^ (row & 15)) * 16) + (j1 & 7) * 2) = f16b(eb * inv);
    }
  }
  LGKM0(); BAR();

  // ---- PV ----
  char* Fb = ldsb;
  auto STAGE_F = [&](int h){
    char* slot = Fb + (size_t)(h & 1) * 32768;
#pragma unroll
    for (int j = 0; j < 2; j++){
      const int o = j * 1024 + tid;
      const int a = o >> 4, c = o & 15;
      gload_lds16(FT + (size_t)(h * 128 + a) * 32768 + frame * 128 + (c ^ (a & 15)) * 8,
                  slot + (size_t)o * 16);
    }
  };
  STAGE_F(0);

#pragma unroll 1
  for (int h = 0; h < 8; h++){
    if (h + 1 < 8){ STAGE_F(h + 1); VM(2); } else { VM(0); }
    BAR();
    const char* fs = Fb + (size_t)(h & 1) * 32768;
    f16x8 pF[4][2], fF[4][2];
#pragma unroll
    for (int ks = 0; ks < 4; ks++){
#pragma unroll
      for (int m = 0; m < 2; m++){
        const int row = wm * 32 + m * 16 + l15;
        pF[ks][m] = *(const f16x8*)((char*)Pb + row * 256 + (((ks * 4 + lg) ^ (row & 15)) * 16));
      }
#pragma unroll
      for (int n = 0; n < 2; n++){
        const int al = wn * 32 + n * 16 + l15;
        fF[ks][n] = *(const f16x8*)(fs + al * 256 + (((ks * 4 + lg) ^ (al & 15)) * 16));
      }
    }
    LGKM0();
    f32x4 accP[2][2];
#pragma unroll
    for (int m = 0; m < 2; m++)
#pragma unroll
      for (int n = 0; n < 2; n++) accP[m][n] = zero;
    __builtin_amdgcn_s_setprio(1);
#pragma unroll
    for (int ks = 0; ks < 4; ks++)
#pragma unroll
      for (int m = 0; m < 2; m++)
#pragma unroll
        for (int n = 0; n < 2; n++)
          accP[m][n] = __builtin_amdgcn_mfma_f32_16x16x32_f16(pF[ks][m], fF[ks][n], accP[m][n], 0, 0, 0);
    __builtin_amdgcn_s_setprio(0);
#pragma unroll
    for (int m = 0; m < 2; m++)
#pragma unroll
      for (int n = 0; n < 2; n++){
        const int f  = h * 128 + wn * 32 + n * 16 + l15;
        const int r0 = wm * 32 + m * 16 + lg * 4;
#pragma unroll
        for (int q = 0; q < 4; q++)
          outp[((size_t)frame * 128 + r0 + q) * 1024 + f] = accP[m][n][q];
      }
    BAR();
  }
}

// ============================================================================
// Merged prep (unchanged).
// ============================================================================
__global__ __launch_bounds__(256) void k_prep(const float* __restrict__ Wa,
                                              const float* __restrict__ Wb,
                                              const float* __restrict__ Wg,
                                              const float* __restrict__ ba,
                                              unsigned short* __restrict__ Wa2,
                                              unsigned short* __restrict__ Wb2,
                                              unsigned short* __restrict__ WgTh,
                                              float* __restrict__ wv){
  const int b = blockIdx.x;
  if (b < 2048){
    const int row = (b < 1024) ? b : (b - 1024);
    const float* src = (b < 1024) ? Wa : Wb;
    unsigned short* dst = (b < 1024) ? Wa2 : Wb2;
    const int c = threadIdx.x * 4;
    float4 val = *(const float4*)(src + (size_t)row * 1024 + c);
    ushort4 h, l;
    split2h(val.x, h.x, l.x); split2h(val.y, h.y, l.y);
    split2h(val.z, h.z, l.z); split2h(val.w, h.w, l.w);
    *(ushort4*)(dst + (size_t)row * 2048 + c) = h;
    *(ushort4*)(dst + (size_t)row * 2048 + 1024 + c) = l;
  } else if (b < 3072){
    const int row = b - 2048;
    const int c0 = threadIdx.x * 4;
    float4 val = *(const float4*)(Wg + (size_t)row * 1024 + c0);
    float vv[4] = {val.x, val.y, val.z, val.w};
#pragma unroll
    for (int i = 0; i < 4; i++)
      WgTh[(size_t)(c0 + i) * 1024 + row] = f16b(vv[i]);
  } else {
    const int row = (b - 3072) * 4 + (threadIdx.x >> 6);
    const int lane = threadIdx.x & 63;
    float s = 0.f;
#pragma unroll
    for (int j = 0; j < 4; j++){
      const int c = lane * 4 + j * 256;
      float4 wb = *(const float4*)(Wb + (size_t)row * 1024 + c);
      float4 bb = *(const float4*)(ba + c);
      s += wb.x * bb.x + wb.y * bb.y + wb.z * bb.z + wb.w * bb.w;
    }
    for (int o = 32; o; o >>= 1) s += __shfl_xor(s, o);
    if (lane == 0) wv[row] = s;
  }
}

// ---------- launcher ----------
extern "C" void kernel_launch(void* const* d_in, const int* in_sizes, int n_in,
                              void* d_out, int out_size, void* d_ws, size_t ws_size,
                              hipStream_t stream) {
  const float* x  = (const float*)d_in[0];
  const float* Wa = (const float*)d_in[2];
  const float* ba = (const float*)d_in[3];
  const float* Wb = (const float*)d_in[4];
  const float* Wg = (const float*)d_in[6];
  const float* bg = (const float*)d_in[7];

  unsigned short* x2   = (unsigned short*)d_ws;            // 32768 x 1024 fp16 (hi)
  unsigned short* Wa2  = x2 + (size_t)32768 * 1024;        // 1024 x 2048
  unsigned short* Wb2  = Wa2 + (size_t)1024 * 2048;        // 1024 x 2048
  unsigned short* WgTh = Wb2 + (size_t)1024 * 2048;        // 1024 x 1024 (Wg^T fp16)
  unsigned short* MTh  = WgTh + (size_t)1024 * 1024;       // 1024 x 1024 (M^T fp16)
  unsigned short* FT   = MTh + (size_t)1024 * 1024;        // 1024 x 32768 (feats^T fp16)
  float* Mpart = (float*)(FT + (size_t)1024 * 32768);      // 6 x 1024x1024 fp32
  float* wv = Mpart + (size_t)6 * 1048576;                 // 1024
  float* v  = wv + 1024;                                   // 32768
  size_t need = (size_t)((char*)(v + 32768) - (char*)d_ws);
  if (ws_size < need) return;

  unsigned short* y2 = (unsigned short*)d_out;             // yh rows, stride 2048

  k_prep      <<<3328, 256, 0, stream>>>(Wa, Wb, Wg, ba, Wa2, Wb2, WgTh, wv);
  // mt split-K (96 compute-bound blocks) hidden under split_x (memory-bound)
  k_mtx       <<<1120, 512, 0, stream>>>(Wa2, Wb2, Mpart, x, x2, wv, v);
  k_mt_reduce <<<1024, 256, 0, stream>>>(Mpart, MTh);
  // y + featsT interleaved (x2-panel sharing); 256^2 tiles, BK=64 (R17 best)
  k_big       <<<1024, 512, 0, stream>>>(x2, MTh, y2, WgTh, FT, bg);
  // scores (K=1024: yh x xh) -> softmax -> PV
  k_frame     <<<256, 1024, 0, stream>>>(y2, x2, v, FT, (float*)d_out);
}